// Round 9
// baseline (236.111 us; speedup 1.0000x reference)
//
#include <hip/hip_runtime.h>

// CapsuleLayer dynamic routing, MI355X. R12: k-outer pipelined votes producer.
//  - R11 votes (58us, VGPR=56!): compiler refused to hold w4[16] (64 regs)
//    across the b-loop -> re-fetched W per b inside the FMA chain (VALU 13%,
//    3.5 TB/s). R12 makes the live set small+static: k-OUTER dot products.
//    Per i: 4 s_load x (wave-uniform) + 16 independent dwordx4 W loads issue
//    ahead; 16 k-steps of {loaded w-quad -> 16 FMA} into V[4] (16 regs).
//    unroll 2 on i hoists i+1 loads under i's FMAs. VGPR ~110 @ (512,4).
//  - IC=8 per block (bh splits b): pr0 shrinks to 16.8MB (reduce0 nw=256).
//  - XCD swizzle co-locates the bh-pair (shares W[i-range]) on one XCD L2.
//  - Routes/reduces unchanged from R11 (zero-barrier streaming, 32 waves/CU).
//
// route lane layout: lane owns o=[8l,8l+8); d=l>>1, h=l&1; h-combine
// shfl_xor(1); softmax over 32 d's shfl_xor {2,4,8,16,32}.
// Round-2 logits fold: logits2 = votes.(act0+act1).

#define B_  32
#define I_  2048
#define K_  16
#define O_  512
#define IC_ 8     // i's per votes-block
#define NGV 256   // votes i-groups (pr0 leading dim)
#define NGR 256   // route partial slices

// ---------------------------------------------------------------- votes ----
// grid 512 = 256 ig x 2 bh; 512 thr: oq = t&127 (o-quad), bq = t>>7 -> 4 b's.
// Zero LDS, zero barriers. k-outer FMA, 16-deep independent W-load window.
__global__ __launch_bounds__(512, 4)
void votes_kernel(const float* __restrict__ x, const float* __restrict__ W,
                  float* __restrict__ votes, float* __restrict__ pr0)
{
    const int t   = threadIdx.x;
    const int bid = blockIdx.x;
    // XCD swizzle: bh-pair differs only in bit 3 -> same XCD round-robin slot
    const int ig  = (bid & 7) * 32 + (bid >> 4);    // 0..255
    const int bh  = (bid >> 3) & 1;
    const int i0  = ig * IC_;
    const int oq  = t & 127;                        // o-quad
    const int bq  = __builtin_amdgcn_readfirstlane(t >> 7);  // 0..3, wave-uniform
    const int b0  = bh * 16 + bq * 4;

    float4 facc[4];
    #pragma unroll
    for (int bb = 0; bb < 4; ++bb) facc[bb] = make_float4(0.f, 0.f, 0.f, 0.f);

    #pragma unroll 2
    for (int ii = 0; ii < IC_; ++ii) {
        const int i = i0 + ii;

        // x[b][i][:] for 4 b's -- wave-uniform -> s_load_dwordx4 x4 each
        float xs[4][16];
        #pragma unroll
        for (int bb = 0; bb < 4; ++bb) {
            const float4* xp = (const float4*)(x + ((size_t)(b0 + bb) * I_ + i) * K_);
            #pragma unroll
            for (int q = 0; q < 4; ++q) {
                const float4 v = xp[q];
                xs[bb][4*q+0] = v.x; xs[bb][4*q+1] = v.y;
                xs[bb][4*q+2] = v.z; xs[bb][4*q+3] = v.w;
            }
        }

        // 16 independent W-quad loads feed 16 FMA each; V[4]+w = ~20 live regs
        const float4* Wp = (const float4*)(W + (size_t)i * (K_ * O_)) + oq;
        float4 V[4];
        #pragma unroll
        for (int bb = 0; bb < 4; ++bb) V[bb] = make_float4(0.f, 0.f, 0.f, 0.f);
        #pragma unroll
        for (int k = 0; k < K_; ++k) {
            const float4 w = Wp[(size_t)k * (O_ / 4)];
            #pragma unroll
            for (int bb = 0; bb < 4; ++bb) {
                const float xb = xs[bb][k];
                V[bb].x = fmaf(xb, w.x, V[bb].x);
                V[bb].y = fmaf(xb, w.y, V[bb].y);
                V[bb].z = fmaf(xb, w.z, V[bb].z);
                V[bb].w = fmaf(xb, w.w, V[bb].w);
            }
        }

        // votes[b][i][o4] -- wave-contiguous 1KB dwordx4 stores
        #pragma unroll
        for (int bb = 0; bb < 4; ++bb) {
            ((float4*)(votes + ((size_t)(b0 + bb) * I_ + i) * O_))[oq] = V[bb];
            facc[bb].x += V[bb].x; facc[bb].y += V[bb].y;
            facc[bb].z += V[bb].z; facc[bb].w += V[bb].w;
        }
    }

    // pr0[ig][b][o4] (fused round-0 partial)
    #pragma unroll
    for (int bb = 0; bb < 4; ++bb)
        ((float4*)(pr0 + ((size_t)ig * B_ + b0 + bb) * O_))[oq] = facc[bb];
}

// ---------------------------------------------------------------- route ----
// rounds 1/2: grid 2048 = 64 ichunks x 32 b; 256 thr = 4 waves x 8 i.
// Zero barriers, zero LDS, 32 waves/CU. PASS=1: as_=act0; PASS=2: act0+act1.
template<int PASS>
__global__ __launch_bounds__(256)
void route_kernel(const float* __restrict__ votes, const float* __restrict__ act0,
                  const float* __restrict__ act1, float* __restrict__ partial)
{
    const int tid  = threadIdx.x;
    const int lane = tid & 63;
    const int wave = tid >> 6;              // 0..3
    const int b    = blockIdx.x & 31;
    const int ic   = blockIdx.x >> 5;       // 0..63
    const int i0   = ic * 32 + wave * 8;

    float as_[8];
    {
        const float4* p = (const float4*)(act0 + b * O_ + lane * 8);
        float4 f0 = p[0], f1 = p[1];
        as_[0]=f0.x; as_[1]=f0.y; as_[2]=f0.z; as_[3]=f0.w;
        as_[4]=f1.x; as_[5]=f1.y; as_[6]=f1.z; as_[7]=f1.w;
        if (PASS == 2) {
            const float4* q = (const float4*)(act1 + b * O_ + lane * 8);
            float4 g0 = q[0], g1 = q[1];
            as_[0]+=g0.x; as_[1]+=g0.y; as_[2]+=g0.z; as_[3]+=g0.w;
            as_[4]+=g1.x; as_[5]+=g1.y; as_[6]+=g1.z; as_[7]+=g1.w;
        }
    }

    float facc[8];
    #pragma unroll
    for (int j = 0; j < 8; ++j) facc[j] = 0.f;

    #pragma unroll
    for (int ii = 0; ii < 8; ++ii) {
        const float4* vp = (const float4*)(votes + ((size_t)b * I_ + i0 + ii) * O_ + lane * 8);
        const float4 v0 = vp[0], v1 = vp[1];
        const float V[8] = {v0.x, v0.y, v0.z, v0.w, v1.x, v1.y, v1.z, v1.w};
        float p0 = 0.f;
        #pragma unroll
        for (int j = 0; j < 8; ++j) p0 = fmaf(V[j], as_[j], p0);
        p0 += __shfl_xor(p0, 1);            // combine the two a-halves
        // softmax over 32 d's (no max-sub: |logits| small, f32-safe)
        const float e = __expf(p0);
        float s = e;
        s += __shfl_xor(s, 2);
        s += __shfl_xor(s, 4);
        s += __shfl_xor(s, 8);
        s += __shfl_xor(s, 16);
        s += __shfl_xor(s, 32);
        const float r = e * __builtin_amdgcn_rcpf(s);
        #pragma unroll
        for (int j = 0; j < 8; ++j) facc[j] = fmaf(r, V[j], facc[j]);
    }

    float4* dst = (float4*)(partial + ((size_t)(ic * 4 + wave) * B_ + b) * O_ + lane * 8);
    dst[0] = make_float4(facc[0], facc[1], facc[2], facc[3]);
    dst[1] = make_float4(facc[4], facc[5], facc[6], facc[7]);
}

// --------------------------------------------------------------- reduce ----
// sum nw partials ([nw][B][O] as float4 columns) -> *scale + bias -> squash
// over A -> out. grid 512 x 256: block covers 8 float4-columns, 32 w-slices.
__global__ __launch_bounds__(256)
void reduce_squash(const float* __restrict__ partial, const float* __restrict__ bias,
                   float scale, int nw, float* __restrict__ out)
{
    const int t   = threadIdx.x;
    const int g4  = blockIdx.x * 8 + (t & 7);    // float4 column, 0..4095
    const int sl  = t >> 3;                      // w-slice 0..31
    const int per = nw >> 5;                     // nw/32
    const float4* p4 = (const float4*)partial;
    float4 s = make_float4(0.f, 0.f, 0.f, 0.f);
    #pragma unroll 8
    for (int w = sl * per; w < sl * per + per; ++w) {
        const float4 v = p4[(size_t)w * (B_ * O_ / 4) + g4];
        s.x += v.x; s.y += v.y; s.z += v.z; s.w += v.w;
    }
    __shared__ float4 red[256];
    red[t] = s;
    __syncthreads();
    if (t < 8) {
        float4 v = red[t];
        #pragma unroll
        for (int r = 1; r < 32; ++r) {
            const float4 u = red[t + 8 * r];
            v.x += u.x; v.y += u.y; v.z += u.z; v.w += u.w;
        }
        const float4 bi = ((const float4*)bias)[g4 & 127];
        float4 p;
        p.x = fmaf(v.x, scale, bi.x);
        p.y = fmaf(v.y, scale, bi.y);
        p.z = fmaf(v.z, scale, bi.z);
        p.w = fmaf(v.w, scale, bi.w);
        float nn = p.x*p.x + p.y*p.y + p.z*p.z + p.w*p.w;
        nn += __shfl_xor(nn, 1);     // 4 threads (16 a's) share one d
        nn += __shfl_xor(nn, 2);
        const float sc = sqrtf(nn) / (1.f + nn);
        p.x *= sc; p.y *= sc; p.z *= sc; p.w *= sc;
        ((float4*)out)[g4] = p;
    }
}

extern "C" void kernel_launch(void* const* d_in, const int* in_sizes, int n_in,
                              void* d_out, int out_size, void* d_ws, size_t ws_size,
                              hipStream_t stream) {
    const float* x    = (const float*)d_in[0];   // [32,2048,16]
    const float* W    = (const float*)d_in[1];   // [2048,16,512]
    const float* bias = (const float*)d_in[2];   // [512]
    float* out = (float*)d_out;                  // [32,512]

    float* votes   = (float*)d_ws;                       // 32*2048*512 f32 = 134.2 MB
    float* pr0     = votes + (size_t)B_ * I_ * O_;       // 256*32*512 f32 = 16.8 MB
    float* partial = pr0 + (size_t)NGV * B_ * O_;        // 256*32*512 f32 = 16.8 MB
    float* act0    = partial + (size_t)NGR * B_ * O_;    // 64 KB
    float* act1    = act0 + B_ * O_;                     // 64 KB

    votes_kernel<<<512, 512, 0, stream>>>(x, W, votes, pr0);
    reduce_squash<<<512, 256, 0, stream>>>(pr0, bias, 1.f / 32.f, NGV, act0);
    route_kernel<1><<<2048, 256, 0, stream>>>(votes, act0, nullptr, partial);
    reduce_squash<<<512, 256, 0, stream>>>(partial, bias, 1.f, NGR, act1);
    route_kernel<2><<<2048, 256, 0, stream>>>(votes, act0, act1, partial);
    reduce_squash<<<512, 256, 0, stream>>>(partial, bias, 1.f, NGR, out);
}

// Round 10
// 186.486 us; speedup vs baseline: 1.2661x; 1.2661x over previous
//
#include <hip/hip_runtime.h>

// CapsuleLayer dynamic routing, MI355X. R13: R5 structure + register W-window.
//  - 10-round consolidation: recompute-pipeline (R3/R5, 188.8us) beats
//    materialize-pipeline (best 212.8) on fundamental traffic (320MB vs
//    470MB+). Its sweeps ran 40us vs ~7-14us pipe floor purely from
//    scheduling: VGPR=52 -> compiler kept ~2 ds_read_b128 in flight,
//    serializing read->lgkmcnt->32FMA per k.
//  - R13 changes ONLY the inner loop: per half-k phase, 16 independent
//    ds_read_b128 into named float4 windows (wr0[8],wr1[8]), then 8kx32 FMA.
//    Static indexing (full unroll) keeps windows in VGPRs; compiler emits
//    batched reads + counted lgkmcnt, and hoists next-phase loads under
//    current FMAs. PASS2 folds a1 into as_=a0+a1 (dot linearity) to pay
//    the VGPR bill: ~175 live < 256 cap at 2 blocks/CU.
//  - Everything else is R5 verbatim: 512 blocks x 256 thr, glds-dbuf
//    staging w/ pre-swizzled source, one barrier per ii, XCD-pair swizzle.
//
// Lane layout: lane l owns d = l>>1, h = l&1, outputs o = d*16 + h*8 + j.
// a-half combine: shfl_xor(1); softmax over D: shfl_xor {2,4,8,16,32}.
// LDS W layout (per half): float idx = jq*4096 + k*256 + (d*2+h)*4 + (j&3).
// x loaded via wave-uniform (SGPR) scalar loads.

#define B_  32
#define I_  2048
#define K_  16
#define O_  512
#define NG_ 256   // i-groups (partial-buffer leading dim)
#define IC_ 8     // i's per group

#define GLB(p)  ((const __attribute__((address_space(1))) void*)(p))
#define LDSP(p) ((__attribute__((address_space(3))) void*)(p))

template<int PASS>
__global__ __launch_bounds__(256, 2)
void sweep_kernel(const float* __restrict__ x, const float* __restrict__ W,
                  const float* __restrict__ act0_g, const float* __restrict__ act1_g,
                  float* __restrict__ partial)
{
    const int tid  = threadIdx.x;
    const int lane = tid & 63;
    const int wave = tid >> 6;              // 0..3
    const int bid  = blockIdx.x;
    // XCD-pair swizzle: xcd = bid&7 (round-robin), pair differs only in bit 3
    const int ig   = (bid & 7) * 32 + (bid >> 4);   // 0..255
    const int bh   = (bid >> 3) & 1;                 // batch half
    const int d    = lane >> 1;             // 0..31
    const int h    = lane & 1;
    const int obase = d * 16 + h * 8;       // lane's first o

    // wave-uniform batch base (forces SGPR so x loads go scalar)
    const int wv    = __builtin_amdgcn_readfirstlane(wave);
    const int bbase = bh * 16 + wv * 4;

    __shared__ float sW[2][K_ * O_];        // 2 x 32 KB, permuted W[i] tiles

    // per-lane pre-swizzled source byte offsets: slot s -> global float4 f
    // (bijection verified on [0,2048))
    int voff[8];
    #pragma unroll
    for (int c = 0; c < 8; ++c) {
        const int s = c * 256 + wave * 64 + lane;       // 16B slot index
        const int f = ((s >> 10) & 1) | ((s & 1) << 1)
                    | (((s >> 1) & 31) << 2) | (((s >> 6) & 15) << 7);
        voff[c] = f << 4;                               // byte offset
    }

    float facc[4][8];
    #pragma unroll
    for (int bb = 0; bb < 4; ++bb)
        #pragma unroll
        for (int j = 0; j < 8; ++j) facc[bb][j] = 0.f;

    // as_ = a0 (PASS1) or a0+a1 (PASS2): round-2 logits = V.(a0+a1)
    float as_[4][8];
    if (PASS >= 1) {
        #pragma unroll
        for (int bb = 0; bb < 4; ++bb) {
            const float4* p = (const float4*)(act0_g + (bbase + bb) * O_ + obase);
            float4 f0 = p[0], f1 = p[1];
            as_[bb][0]=f0.x; as_[bb][1]=f0.y; as_[bb][2]=f0.z; as_[bb][3]=f0.w;
            as_[bb][4]=f1.x; as_[bb][5]=f1.y; as_[bb][6]=f1.z; as_[bb][7]=f1.w;
            if (PASS == 2) {
                const float4* q = (const float4*)(act1_g + (bbase + bb) * O_ + obase);
                float4 g0 = q[0], g1 = q[1];
                as_[bb][0]+=g0.x; as_[bb][1]+=g0.y; as_[bb][2]+=g0.z; as_[bb][3]+=g0.w;
                as_[bb][4]+=g1.x; as_[bb][5]+=g1.y; as_[bb][6]+=g1.z; as_[bb][7]+=g1.w;
            }
        }
    }

    // prologue: stage W[i0] into buf 0
    {
        const char* gb = (const char*)(W + (size_t)(ig * IC_) * (K_ * O_));
        #pragma unroll
        for (int c = 0; c < 8; ++c)
            __builtin_amdgcn_global_load_lds(GLB(gb + voff[c]),
                LDSP(&sW[0][(c * 256 + wave * 64) * 4]), 16, 0, 0);
    }

    #pragma unroll 1
    for (int ii = 0; ii < IC_; ++ii) {
        const int i = ig * IC_ + ii;
        // implicit s_waitcnt vmcnt(0) + barrier: buf[ii&1] staged, prior reads done
        __syncthreads();
        // issue next tile's stage into the other half (drains at next barrier)
        if (ii + 1 < IC_) {
            const char* gb = (const char*)(W + (size_t)(i + 1) * (K_ * O_));
            float* nbuf = sW[(ii + 1) & 1];
            #pragma unroll
            for (int c = 0; c < 8; ++c)
                __builtin_amdgcn_global_load_lds(GLB(gb + voff[c]),
                    LDSP(&nbuf[(c * 256 + wave * 64) * 4]), 16, 0, 0);
        }
        const float* cbuf = sW[ii & 1];

        // x for this wave's 4 b's: wave-uniform scalar loads (SGPRs)
        float xs[4][16];
        #pragma unroll
        for (int bb = 0; bb < 4; ++bb) {
            const float4* xp = (const float4*)(x + ((size_t)(bbase + bb) * I_ + i) * K_);
            #pragma unroll
            for (int q = 0; q < 4; ++q) {
                float4 v = xp[q];
                xs[bb][4*q+0]=v.x; xs[bb][4*q+1]=v.y; xs[bb][4*q+2]=v.z; xs[bb][4*q+3]=v.w;
            }
        }

        // V[bb][j]: two half-k phases, each = 16 independent ds_read_b128
        // into named register windows, THEN the 8kx32 FMA block.
        float V[4][8];
        #pragma unroll
        for (int bb = 0; bb < 4; ++bb)
            #pragma unroll
            for (int j = 0; j < 8; ++j) V[bb][j] = 0.f;

        #pragma unroll
        for (int kh = 0; kh < 2; ++kh) {
            float4 wr0[8], wr1[8];
            #pragma unroll
            for (int kq = 0; kq < 8; ++kq) {
                const int k = kh * 8 + kq;
                wr0[kq] = *(const float4*)&cbuf[k * 256 + lane * 4];
                wr1[kq] = *(const float4*)&cbuf[4096 + k * 256 + lane * 4];
            }
            #pragma unroll
            for (int kq = 0; kq < 8; ++kq) {
                const int k = kh * 8 + kq;
                const float w[8] = {wr0[kq].x, wr0[kq].y, wr0[kq].z, wr0[kq].w,
                                    wr1[kq].x, wr1[kq].y, wr1[kq].z, wr1[kq].w};
                #pragma unroll
                for (int bb = 0; bb < 4; ++bb) {
                    const float xb = xs[bb][k];
                    #pragma unroll
                    for (int j = 0; j < 8; ++j) V[bb][j] = fmaf(xb, w[j], V[bb][j]);
                }
            }
        }

        #pragma unroll
        for (int bb = 0; bb < 4; ++bb) {
            if (PASS == 0) {
                #pragma unroll
                for (int j = 0; j < 8; ++j) facc[bb][j] += V[bb][j];
            } else {
                float p0 = 0.f;
                #pragma unroll
                for (int j = 0; j < 8; ++j) p0 = fmaf(V[bb][j], as_[bb][j], p0);
                p0 += __shfl_xor(p0, 1);        // combine the two a-halves
                // softmax over 32 d's (no max-sub: |logits| small, f32-safe)
                const float e = __expf(p0);
                float s = e;
                s += __shfl_xor(s, 2);
                s += __shfl_xor(s, 4);
                s += __shfl_xor(s, 8);
                s += __shfl_xor(s, 16);
                s += __shfl_xor(s, 32);
                const float r = e * __builtin_amdgcn_rcpf(s);
                #pragma unroll
                for (int j = 0; j < 8; ++j)
                    facc[bb][j] = fmaf(r, V[bb][j], facc[bb][j]);
            }
        }
    }

    // flush per-(ig) partials
    #pragma unroll
    for (int bb = 0; bb < 4; ++bb) {
        const int b = bbase + bb;
        float4* dst = (float4*)(partial + ((size_t)ig * B_ + b) * O_ + obase);
        dst[0] = make_float4(facc[bb][0], facc[bb][1], facc[bb][2], facc[bb][3]);
        dst[1] = make_float4(facc[bb][4], facc[bb][5], facc[bb][6], facc[bb][7]);
    }
}

// sum NG_ partials -> *scale + bias -> squash over A -> out
// 512 wgs x 256 thr; wg covers 32 g's; 8 w-slices of 32 reduced via LDS.
__global__ __launch_bounds__(256)
void reduce_squash(const float* __restrict__ partial, const float* __restrict__ bias,
                   float scale, float* __restrict__ out)
{
    const int t  = threadIdx.x;
    const int g  = blockIdx.x * 32 + (t & 31);   // b*512 + o
    const int sl = t >> 5;                       // w-slice 0..7
    float s = 0.f;
    #pragma unroll
    for (int w = sl * 32; w < sl * 32 + 32; ++w)
        s += partial[(size_t)w * (B_ * O_) + g];
    __shared__ float red[256];
    red[t] = s;
    __syncthreads();
    if (t < 32) {
        float v = red[t];
        #pragma unroll
        for (int r = 1; r < 8; ++r) v += red[t + 32 * r];
        const float p = fmaf(v, scale, bias[g & (O_ - 1)]);
        float nn = p * p;
        nn += __shfl_xor(nn, 1);
        nn += __shfl_xor(nn, 2);
        nn += __shfl_xor(nn, 4);
        nn += __shfl_xor(nn, 8);
        out[g] = p * sqrtf(nn) / (1.f + nn);
    }
}

extern "C" void kernel_launch(void* const* d_in, const int* in_sizes, int n_in,
                              void* d_out, int out_size, void* d_ws, size_t ws_size,
                              hipStream_t stream) {
    const float* x    = (const float*)d_in[0];   // [32,2048,16]
    const float* W    = (const float*)d_in[1];   // [2048,16,512]
    const float* bias = (const float*)d_in[2];   // [512]
    float* out = (float*)d_out;                  // [32,512]

    float* partial = (float*)d_ws;                       // NG_*32*512 f32 = 16.8 MB
    float* act0    = partial + (size_t)NG_ * B_ * O_;    // 64 KB
    float* act1    = act0 + B_ * O_;                     // 64 KB

    sweep_kernel<0><<<NG_ * 2, 256, 0, stream>>>(x, W, nullptr, nullptr, partial);
    reduce_squash<<<512, 256, 0, stream>>>(partial, bias, 1.f / 32.f, act0);
    sweep_kernel<1><<<NG_ * 2, 256, 0, stream>>>(x, W, act0, nullptr, partial);
    reduce_squash<<<512, 256, 0, stream>>>(partial, bias, 1.f, act1);
    sweep_kernel<2><<<NG_ * 2, 256, 0, stream>>>(x, W, act0, act1, partial);
    reduce_squash<<<512, 256, 0, stream>>>(partial, bias, 1.f, out);
}